// Round 13
// baseline (816.268 us; speedup 1.0000x reference)
//
#include <hip/hip_runtime.h>
#include <math.h>

#define TT 36
#define NP 160
#define KDIM 641
#define PP 512
#define KPAD 704          // transposed-x row stride
#define NU 321            // pair-units: u=0 const col; 1..160 cos; 161..320 sin
#define NSLOT 384         // padded unit slots (321..383 stay zero)
#define BT 384            // 6 waves
#define NW 6
#define LAM 0.1f
#define EPSW 0.01f
#define NITER 200
#define NPOW 160

// ---------------- dictionary ----------------
__global__ void k_build_dic(const float* __restrict__ rr, const float* __restrict__ th,
                            float* __restrict__ D, float* __restrict__ outD) {
  int idx = blockIdx.x * blockDim.x + threadIdx.x;
  if (idx >= TT * KDIM) return;
  int t = idx / KDIM, k = idx % KDIM;
  float v;
  if (k == 0) {
    v = 1.0f;
  } else {
    int g = (k - 1) / NP;     // 0:p*cos 1:m*cos 2:p*sin 3:m*sin
    int p = (k - 1) % NP;
    float ft = (float)t;
    float pw = powf(rr[p], ft);
    if ((g == 1 || g == 3) && (t & 1)) pw = -pw;
    float ang = ft * th[p];
    v = pw * ((g < 2) ? cosf(ang) : sinf(ang));
  }
  D[idx] = v;
  outD[idx] = v;
}

// ---------------- G = D D^T (36x36) ----------------
__global__ void k_G(const float* __restrict__ D, float* __restrict__ G) {
  int idx = blockIdx.x * blockDim.x + threadIdx.x;
  if (idx >= TT * TT) return;
  int i = idx / TT, j = idx % TT;
  float s = 0.0f;
  for (int k = 0; k < KDIM; ++k) s = fmaf(D[i * KDIM + k], D[j * KDIM + k], s);
  G[idx] = s;
}

// ---------------- power iteration on 36x36 (one wave): L = ||DtD||_2; mu table ----------------
__global__ void k_power(const float* __restrict__ G, float* __restrict__ Lb,
                        float* __restrict__ mug) {
  int lane = threadIdx.x;   // blockDim = 64
  float g[TT];
#pragma unroll
  for (int j = 0; j < TT; ++j) g[j] = (lane < TT) ? G[lane * TT + j] : 0.0f;
  float v = (lane < TT) ? 1.0f : 0.0f;
  for (int it = 0; it < NPOW; ++it) {
    float u = 0.0f;
#pragma unroll
    for (int j = 0; j < TT; ++j) u = fmaf(g[j], __shfl(v, j, 64), u);
    float s = u * u;
#pragma unroll
    for (int o = 32; o >= 1; o >>= 1) s += __shfl_xor(s, o, 64);
    v = u * rsqrtf(s);
  }
  float u = 0.0f;
#pragma unroll
  for (int j = 0; j < TT; ++j) u = fmaf(g[j], __shfl(v, j, 64), u);
  float num = v * u, den = v * v;
#pragma unroll
  for (int o = 32; o >= 1; o >>= 1) {
    num += __shfl_xor(num, o, 64);
    den += __shfl_xor(den, o, 64);
  }
  if (lane == 0) {
    float L = num / den;   // Rayleigh quotient = lambda_max
    Lb[0] = L;
    Lb[1] = 1.0f / L;
    Lb[3] = 0.0f;          // reset norm accumulator (graph-replay safe)
    float t = 1.0f;
    for (int i = 0; i < NITER; ++i) {
      float tn = 0.5f * (1.0f + sqrtf(1.0f + 4.0f * t * t));
      mug[i] = (t - 1.0f) / tn;
      t = tn;
    }
  }
}

// ---- DPP wave-64 sum; total valid in lane 63 ----
template <int C>
__device__ __forceinline__ float dppadd(float v) {
  int t = __builtin_amdgcn_update_dpp(0, __float_as_int(v), C, 0xf, 0xf, true);
  return v + __int_as_float(t);
}
__device__ __forceinline__ float wave_sum63(float v) {
  v = dppadd<0xB1>(v);    // quad_perm [1,0,3,2]
  v = dppadd<0x4E>(v);    // quad_perm [2,3,0,1]
  v = dppadd<0x141>(v);   // row_half_mirror
  v = dppadd<0x140>(v);   // row_mirror
  v = dppadd<0x142>(v);   // row_bcast15
  v = dppadd<0x143>(v);   // row_bcast31
  return v;               // lane 63 holds the total
}

// plus-group column index of pair-unit u (u < NU)
__device__ __forceinline__ int colmap(int u) {
  return (u == 0) ? 0 : ((u < 161) ? u : u + 160);
}

// ---------------- persistent per-round FISTA: one column per block, 6 waves ----------------
__global__ __launch_bounds__(BT, 1) void k_round(
    const float* __restrict__ Dg, const float* __restrict__ X,
    float* __restrict__ Lb, const float* __restrict__ mug,
    const float* __restrict__ xprev, float* __restrict__ xout,
    int first, int last) {
  __shared__ __align__(16) float2 ylds2[NSLOT];   // slot u = (yP_u, yM_u); 321..383 stay (0,0)
  __shared__ float pbuf[NW * NSLOT];              // per-wave phase-2 partials (disjoint)
  __shared__ float muLDS[NITER];
  __shared__ float rn[NW];

  const int tid  = threadIdx.x;
  const int lane = tid & 63;
  const int w    = tid >> 6;          // wave 0..5; rows t = w + 6i, i<6 (parity = w&1)
  const float sgn = (w & 1) ? -1.0f : 1.0f;
  const int p    = blockIdx.x;        // column

  const float Linv = Lb[1];
  const float sqL  = sqrtf(Linv);
  const float lamL = LAM * Linv;

  // ---- unit ownership: one per thread, tid < NU
  const bool act = (tid < NU);
  const int u    = act ? tid : 0;
  const int kP   = colmap(u);
  const int kM   = (u == 0) ? 0 : kP + 160;

  // ---- Dq[i][j] = sqrt(Linv) * D[w+6i][colmap(lane+64j)]; zero for pad units
  float Dq[6][6];
#pragma unroll
  for (int i = 0; i < 6; ++i)
#pragma unroll
    for (int j = 0; j < 6; ++j) {
      const int ua = lane + 64 * j;
      Dq[i][j] = (ua < NU) ? Dg[(w + 6 * i) * KDIM + colmap(ua)] * sqL : 0.0f;
    }

  // ---- c0 = Linv*(D^T x_col) via even/odd split (one-time global reads)
  float cmP, cpP, cmM, cpM;
  {
    float sE0 = 0.f, sO0 = 0.f;
#pragma unroll 6
    for (int t = 0; t < TT; ++t) {
      const float dv = act ? Dg[t * KDIM + kP] : 0.0f;
      const float xv = X[t * PP + p];             // block-uniform
      if (t & 1) sO0 = fmaf(dv, xv, sO0);
      else       sE0 = fmaf(dv, xv, sE0);
    }
    const float c0P = (sE0 + sO0) * Linv, c0M = (sE0 - sO0) * Linv;
    float wlP = lamL, wlM = lamL;
    if (!first) {
      const float nl = lamL * Lb[2];              // lam*Linv/||wr||
      wlP = nl / (fabsf(xprev[p * KPAD + kP]) + EPSW);
      wlM = nl / (fabsf(xprev[p * KPAD + ((u > 0) ? kM : kP)]) + EPSW);
    }
    cmP = c0P - wlP; cpP = c0P + wlP;
    cmM = c0M - wlM; cpM = c0M + wlM;
  }

  // ---- init LDS
  if (tid < NSLOT) ylds2[tid] = make_float2(0.f, 0.f);
  if (tid < NITER) muLDS[tid] = mug[tid];

  float xP = 0.f, xM = 0.f, yP = 0.f, yM = 0.f;

  __syncthreads();

  for (int it = 0; it < NITER; ++it) {
    // ---- pin Dq in arch VGPRs for this iteration (zero-instruction asm;
    //      parking in AGPR/scratch would cost a copy per iter, so allocator won't)
#pragma unroll
    for (int i = 0; i < 6; ++i)
#pragma unroll
      for (int j = 0; j < 6; ++j)
        asm volatile("" : "+v"(Dq[i][j]));

    // ===== phase 1: z rows t=w+6i: acc = sum_units Dq * (yP ± yM) =====
    float acc[6] = {0.f, 0.f, 0.f, 0.f, 0.f, 0.f};
#pragma unroll
    for (int j = 0; j < 6; ++j) {
      const float2 yv = ylds2[lane + 64 * j];     // ds_read_b64, conflict-free
      const float op = fmaf(sgn, yv.y, yv.x);     // yP ± yM, parity wave-uniform
#pragma unroll
      for (int i = 0; i < 6; ++i) acc[i] = fmaf(Dq[i][j], op, acc[i]);
    }
    // reduce each row; broadcast via SGPR
    float z[6];
#pragma unroll
    for (int i = 0; i < 6; ++i) {
      const float r = wave_sum63(acc[i]);
      z[i] = __int_as_float(__builtin_amdgcn_readlane(__float_as_int(r), 63));
    }
    // ===== phase-2 partials: pw[u] = sum_i Dq[i][u]*z[i] (this wave's rows only) =====
#pragma unroll
    for (int j = 0; j < 6; ++j) {
      float pw = Dq[0][j] * z[0];
#pragma unroll
      for (int i = 1; i < 6; ++i) pw = fmaf(Dq[i][j], z[i], pw);
      pbuf[w * NSLOT + lane + 64 * j] = pw;       // disjoint per wave: no contention
    }
    __syncthreads();

    // ===== owner: sum partials by parity, reconstruct pair rows, shrink, momentum =====
    const float mu = muLDS[it];
    if (act) {
      const float sE = (pbuf[0 * NSLOT + u] + pbuf[2 * NSLOT + u]) + pbuf[4 * NSLOT + u];
      const float sO = (pbuf[1 * NSLOT + u] + pbuf[3 * NSLOT + u]) + pbuf[5 * NSLOT + u];
      const float sP = sE + sO, sM = sE - sO;     // = Linv*(DtD y) rows kP,kM
      float uu, xn;
      uu = yP - sP; xn = fmaxf(0.f, uu + cmP) + fminf(0.f, uu + cpP);
      yP = fmaf(mu, xn - xP, xn); xP = xn;
      uu = yM - sM; xn = fmaxf(0.f, uu + cmM) + fminf(0.f, uu + cpM);
      yM = fmaf(mu, xn - xM, xn); xM = xn;
      ylds2[u] = make_float2(yP, (u > 0) ? yM : 0.0f);
    }
    __syncthreads();
  }

  // ---- emit x
  if (act) {
    if (last) {
      xout[kP * PP + p] = xP;
      if (u > 0) xout[kM * PP + p] = xM;
    } else {
      xout[p * KPAD + kP] = xP;                   // transposed for next round
      if (u > 0) xout[p * KPAD + kM] = xM;
    }
  }

  // ---- fused reweight-norm accumulation: sum of wr^2 over this column
  if (!last) {
    float s = 0.0f;
    if (act) {
      const float rP = 1.0f / (fabsf(xP) + EPSW);
      s = rP * rP;
      if (u > 0) { const float rM = 1.0f / (fabsf(xM) + EPSW); s += rM * rM; }
    }
    s = wave_sum63(s);
    if (lane == 63) rn[w] = s;
    __syncthreads();
    if (tid == 0) {
      float tot = 0.f;
#pragma unroll
      for (int i = 0; i < NW; ++i) tot += rn[i];
      atomicAdd(&Lb[3], tot);                     // global atomic: fine
    }
  }
}

// ---------------- finalize norm: Lb[2] = 1/||wr||, reset accumulator ----------------
__global__ void k_norm(float* __restrict__ Lb) {
  if (threadIdx.x == 0) {
    Lb[2] = 1.0f / sqrtf(Lb[3]);
    Lb[3] = 0.0f;
  }
}

// ---------------- host ----------------
extern "C" void kernel_launch(void* const* d_in, const int* in_sizes, int n_in,
                              void* d_out, int out_size, void* d_ws, size_t ws_size,
                              hipStream_t stream) {
  const float* x  = (const float*)d_in[0];
  const float* rr = (const float*)d_in[1];
  const float* th = (const float*)d_in[2];
  float* out = (float*)d_out;
  float* ws  = (float*)d_ws;

  size_t off = 0;
  auto alloc = [&](size_t n) {
    float* p = ws + off;
    off += (n + 63) & ~(size_t)63;
    return p;
  };
  float* D    = alloc((size_t)TT * KDIM);
  float* G    = alloc(TT * TT);
  float* Lb   = alloc(16);
  float* mug  = alloc(NITER);
  float* xa   = alloc((size_t)PP * KPAD);   // transposed intermediate x
  if (off * sizeof(float) > ws_size) return;

  k_build_dic<<<(TT * KDIM + 255) / 256, 256, 0, stream>>>(rr, th, D, out + (size_t)KDIM * PP);
  k_G<<<(TT * TT + 255) / 256, 256, 0, stream>>>(D, G);
  k_power<<<1, 64, 0, stream>>>(G, Lb, mug);

  for (int r = 0; r < 3; ++r) {
    const int first = (r == 0), last = (r == 2);
    float* xo = last ? out : xa;
    k_round<<<PP, BT, 0, stream>>>(D, x, Lb, mug, xa, xo, first, last);
    if (!last) k_norm<<<1, 64, 0, stream>>>(Lb);
  }
}